// Round 4
// baseline (80.989 us; speedup 1.0000x reference)
//
#include <hip/hip_runtime.h>
#include <math.h>

#define N 512

__global__ void init_out(float* out) { out[0] = 0.0f; }

// ---------------- Fully fused kernel ----------------
// 256 blocks x 512 threads. Block b owns rows b and b+256 (they share
// labels[b], hence one ld table and the same multiplicity rule).
// Dist phase: wave w covers j in [w*64,(w+1)*64); lane = (jl<<3)|ds:
// 8 j-columns x 8 d-slices. fi slices live in registers (a0/a1), fj is
// read per-lane (one 128B line per slice, L1-cached across the 8 float4s).
__global__ __launch_bounds__(512) void rnc_fused_kernel(
    const float* __restrict__ F,       // [256,2,256]
    const float* __restrict__ labels,  // [256,1]
    float* __restrict__ out)
{
    const int b    = blockIdx.x;   // 0..255
    const int t    = threadIdx.x;  // 0..511
    const int w    = t >> 6;       // wave 0..7
    const int lane = t & 63;
    const int jl   = lane >> 3;    // 0..7 : j within batch
    const int ds   = lane & 7;     // 0..7 : d-slice (32 floats each)

    __shared__ __align__(16) float sh_e[2][N];    // e values per row, diag = 0
    __shared__ __align__(16) float sh_E2[2][256]; // folded e[j'] + e[j'+256]
    __shared__ __align__(16) float sh_ld[256];    // |lab_b - lab_j'|
    __shared__ float sh_red[8];

    // ld table (exact same fp32 ops as reference label_diffs)
    const float lab_b = labels[b];
    if (t < 256) sh_ld[t] = fabsf(lab_b - labels[t]);

    // fi slices in registers: f[b] = features[b][0][:], f[b+256] = features[b][1][:]
    // contiguous at F + b*512.
    const float* fb = F + (size_t)b * 512;
    float4 a0[8], a1[8];
    #pragma unroll
    for (int q = 0; q < 8; ++q) {
        a0[q] = *reinterpret_cast<const float4*>(fb + ds * 32 + q * 4);
        a1[q] = *reinterpret_cast<const float4*>(fb + 256 + ds * 32 + q * 4);
    }

    float slog = 0.0f;  // this thread's share of sum-of-logits

    #pragma unroll
    for (int batch = 0; batch < 8; ++batch) {
        const int j = w * 64 + batch * 8 + jl;
        const float* fj = F + (size_t)(j & 255) * 512 + (size_t)(j >> 8) * 256;
        float acc0 = 0.0f, acc1 = 0.0f;
        #pragma unroll
        for (int q = 0; q < 8; ++q) {
            const float4 v = *reinterpret_cast<const float4*>(fj + ds * 32 + q * 4);
            const float d00 = a0[q].x - v.x, d01 = a0[q].y - v.y;
            const float d02 = a0[q].z - v.z, d03 = a0[q].w - v.w;
            acc0 += d00 * d00 + d01 * d01 + d02 * d02 + d03 * d03;
            const float d10 = a1[q].x - v.x, d11 = a1[q].y - v.y;
            const float d12 = a1[q].z - v.z, d13 = a1[q].w - v.w;
            acc1 += d10 * d10 + d11 * d11 + d12 * d12 + d13 * d13;
        }
        // reduce partial dots across the 8 d-slice lanes
        acc0 += __shfl_xor(acc0, 1, 64);
        acc0 += __shfl_xor(acc0, 2, 64);
        acc0 += __shfl_xor(acc0, 4, 64);
        acc1 += __shfl_xor(acc1, 1, 64);
        acc1 += __shfl_xor(acc1, 2, 64);
        acc1 += __shfl_xor(acc1, 4, 64);
        // lane ds==r finalizes row r for this j
        if (ds < 2) {
            const float sq    = ds ? acc1 : acc0;
            const float logit = -0.5f * sqrtf(sq);   // TEMP=2; diag sq is exactly 0
            slog += logit;                           // diag adds -0.0
            const int diag = b + (ds << 8);
            sh_e[ds][j] = (j == diag) ? 0.0f : expf(logit);
        }
    }
    __syncthreads();

    // exact 2-fold (order-invariant single add), same as round 3
    {
        const int kp = t & 255;
        const int r  = t >> 8;
        sh_E2[r][kp] = sh_e[r][kp] + sh_e[r][kp + 256];
    }
    __syncthreads();

    // neg + log: thread t -> row r = t>>8, k' = t&255. All LDS reads are
    // wave-uniform (broadcast). Accumulation order identical to round 3.
    const int   kp  = t & 255;
    const int   r   = t >> 8;
    const float ldk = sh_ld[kp];
    const float* E2r = sh_E2[r];
    float ng0 = 0, ng1 = 0, ng2 = 0, ng3 = 0;
    #pragma unroll 8
    for (int j = 0; j < 256; j += 4) {
        const float4 ldv = *reinterpret_cast<const float4*>(&sh_ld[j]);
        const float4 ev  = *reinterpret_cast<const float4*>(&E2r[j]);
        ng0 += (ldv.x >= ldk) ? ev.x : 0.0f;
        ng1 += (ldv.y >= ldk) ? ev.y : 0.0f;
        ng2 += (ldv.z >= ldk) ? ev.z : 0.0f;
        ng3 += (ldv.w >= ldk) ? ev.w : 0.0f;
    }
    const float neg = (ng0 + ng1) + (ng2 + ng3);
    // class k' = b has 1 member among k != i (self excluded), others 2
    const float m = (kp == b) ? 1.0f : 2.0f;

    // per-thread contribution: + m*log(neg) - (sum of logits this thread made)
    float v = m * logf(neg) - slog;

    #pragma unroll
    for (int off = 32; off > 0; off >>= 1)
        v += __shfl_xor(v, off, 64);
    if (lane == 0) sh_red[w] = v;
    __syncthreads();
    if (t == 0) {
        float s = ((sh_red[0] + sh_red[1]) + (sh_red[2] + sh_red[3])) +
                  ((sh_red[4] + sh_red[5]) + (sh_red[6] + sh_red[7]));
        atomicAdd(out, s * (1.0f / (512.0f * 511.0f)));
    }
}

extern "C" void kernel_launch(void* const* d_in, const int* in_sizes, int n_in,
                              void* d_out, int out_size, void* d_ws, size_t ws_size,
                              hipStream_t stream) {
    const float* features = (const float*)d_in[0];  // (256, 2, 256) fp32
    const float* labels   = (const float*)d_in[1];  // (256, 1) fp32
    float* out = (float*)d_out;

    init_out<<<1, 1, 0, stream>>>(out);
    rnc_fused_kernel<<<256, 512, 0, stream>>>(features, labels, out);
}

// Round 7
// 79.701 us; speedup vs baseline: 1.0162x; 1.0162x over previous
//
#include <hip/hip_runtime.h>
#include <math.h>

#define N 512
#define D 256
// ws layout: folded E2 table 512x256 floats, then 512 A-partials
#define PART_OFF (512 * 256)
#define WS_FLOATS (PART_OFF + 512)
#define WS_BYTES (WS_FLOATS * sizeof(float))

__device__ __forceinline__ const float* frow(const float* F, int g) {
    // f[g][:] = features[(g%256), (g/256), :]
    return F + (size_t)(g & 255) * 512 + (size_t)(g >> 8) * 256;
}

// ================= Kernel A': dist + in-register fold =================
// 512 blocks x 256 thr. Block = (i-group blk>>3 : 8 rows) x (j-slice blk&7 :
// 32 cols j'), computing BOTH j' and j'+256 so E2 = e_lo + e_hi folds in
// registers (exact single add, proven round 3/4). One thread zeroes out[0]
// (single writer; readers are in the next dispatch -> stream-ordered).
__global__ __launch_bounds__(256) void rnc_distA(
    const float* __restrict__ F, float* __restrict__ ws,
    float* __restrict__ out)
{
    const int blk = blockIdx.x;   // 0..511
    const int t   = threadIdx.x;  // 0..255
    const int jl  = t >> 3;       // 0..31
    const int ds  = t & 7;        // 0..7

    __shared__ float sh_fi[8 * 256];
    __shared__ float sh_red[4];

    if (blk == 0 && t == 0) out[0] = 0.0f;

    const int i0 = (blk >> 3) * 8;
    const int jp = (blk & 7) * 32 + jl;      // j' in [0,256)
    const int gi = i0 + ds;                  // row this lane finalizes

    // preload both fj slices (128B contiguous per lane; issued early)
    const float* fjlo = frow(F, jp);
    const float* fjhi = frow(F, jp + 256);
    float4 b0[8], b1[8];
    #pragma unroll
    for (int q = 0; q < 8; ++q) {
        b0[q] = *reinterpret_cast<const float4*>(fjlo + ds * 32 + q * 4);
        b1[q] = *reinterpret_cast<const float4*>(fjhi + ds * 32 + q * 4);
    }

    // stage 8 fi rows, XOR-swizzled (verbatim round 3)
    #pragma unroll
    for (int r = 0; r < 8; ++r)
        sh_fi[r * 256 + (t ^ ((t >> 3) & 28))] = frow(F, i0 + r)[t];
    __syncthreads();

    float slog = 0.0f;
    float elo, ehi;

    // ---- h = 0 : j = jp ----
    {
        float acc[8] = {0, 0, 0, 0, 0, 0, 0, 0};
        #pragma unroll
        for (int q = 0; q < 8; ++q) {
            const int eb = ds * 32 + ((q * 4) ^ (ds << 2));
            #pragma unroll
            for (int r = 0; r < 8; ++r) {
                const float4 a = *reinterpret_cast<const float4*>(&sh_fi[r * 256 + eb]);
                const float d0 = a.x - b0[q].x, d1 = a.y - b0[q].y;
                const float d2 = a.z - b0[q].z, d3 = a.w - b0[q].w;
                acc[r] += d0 * d0 + d1 * d1 + d2 * d2 + d3 * d3;
            }
        }
        #pragma unroll
        for (int r = 0; r < 8; ++r) {
            acc[r] += __shfl_xor(acc[r], 1, 64);
            acc[r] += __shfl_xor(acc[r], 2, 64);
            acc[r] += __shfl_xor(acc[r], 4, 64);
        }
        float v = acc[0];
        v = (ds == 1) ? acc[1] : v;  v = (ds == 2) ? acc[2] : v;
        v = (ds == 3) ? acc[3] : v;  v = (ds == 4) ? acc[4] : v;
        v = (ds == 5) ? acc[5] : v;  v = (ds == 6) ? acc[6] : v;
        v = (ds == 7) ? acc[7] : v;
        const float logit = -0.5f * sqrtf(v);     // TEMP=2; diag v is exactly 0
        slog += logit;                            // diag adds -0.0
        elo = (jp == gi) ? 0.0f : expf(logit);
    }
    // ---- h = 1 : j = jp + 256 ----
    {
        float acc[8] = {0, 0, 0, 0, 0, 0, 0, 0};
        #pragma unroll
        for (int q = 0; q < 8; ++q) {
            const int eb = ds * 32 + ((q * 4) ^ (ds << 2));
            #pragma unroll
            for (int r = 0; r < 8; ++r) {
                const float4 a = *reinterpret_cast<const float4*>(&sh_fi[r * 256 + eb]);
                const float d0 = a.x - b1[q].x, d1 = a.y - b1[q].y;
                const float d2 = a.z - b1[q].z, d3 = a.w - b1[q].w;
                acc[r] += d0 * d0 + d1 * d1 + d2 * d2 + d3 * d3;
            }
        }
        #pragma unroll
        for (int r = 0; r < 8; ++r) {
            acc[r] += __shfl_xor(acc[r], 1, 64);
            acc[r] += __shfl_xor(acc[r], 2, 64);
            acc[r] += __shfl_xor(acc[r], 4, 64);
        }
        float v = acc[0];
        v = (ds == 1) ? acc[1] : v;  v = (ds == 2) ? acc[2] : v;
        v = (ds == 3) ? acc[3] : v;  v = (ds == 4) ? acc[4] : v;
        v = (ds == 5) ? acc[5] : v;  v = (ds == 6) ? acc[6] : v;
        v = (ds == 7) ? acc[7] : v;
        const float logit = -0.5f * sqrtf(v);
        slog += logit;
        ehi = (jp + 256 == gi) ? 0.0f : expf(logit);
    }
    // exact fold (single order-invariant add, proven round 3)
    ws[gi * 256 + jp] = elo + ehi;

    // per-block logit-sum -> partial slot (written exactly once, no init needed)
    #pragma unroll
    for (int off = 32; off > 0; off >>= 1)
        slog += __shfl_xor(slog, off, 64);
    if ((t & 63) == 0) sh_red[t >> 6] = slog;
    __syncthreads();
    if (t == 0)
        ws[PART_OFF + blk] = sh_red[0] + sh_red[1] + sh_red[2] + sh_red[3];
}

// ================= Kernel B': neg + log + final accumulate =================
// 512 blocks x 256 thr; block i handles row i (verbatim round-3 B body).
// Each block atomicAdds its scaled m*log(neg) sum into out; block 0 also
// reduces the 512 A-partials and subtracts their scaled sum.
__global__ __launch_bounds__(256) void rnc_negB(
    const float* __restrict__ labels, const float* __restrict__ ws,
    float* __restrict__ out)
{
    const int i = blockIdx.x;   // row 0..511
    const int t = threadIdx.x;  // k' = 0..255
    __shared__ float2 pr[256];
    __shared__ float  sh_red[4];

    const float lab_i = labels[i & 255];
    const float ldk   = fabsf(lab_i - labels[t]);
    pr[t] = make_float2(ldk, ws[i * 256 + t]);
    __syncthreads();

    float ng0 = 0, ng1 = 0, ng2 = 0, ng3 = 0;
    #pragma unroll 8
    for (int j = 0; j < 256; j += 4) {
        const float2 p0 = pr[j + 0], p1 = pr[j + 1];
        const float2 p2 = pr[j + 2], p3 = pr[j + 3];
        ng0 += (p0.x >= ldk) ? p0.y : 0.0f;
        ng1 += (p1.x >= ldk) ? p1.y : 0.0f;
        ng2 += (p2.x >= ldk) ? p2.y : 0.0f;
        ng3 += (p3.x >= ldk) ? p3.y : 0.0f;
    }
    const float neg = (ng0 + ng1) + (ng2 + ng3);
    const float m = (t == (i & 255)) ? 1.0f : 2.0f;  // class i&255 has 1 member
    float partial = m * logf(neg);

    #pragma unroll
    for (int off = 32; off > 0; off >>= 1)
        partial += __shfl_xor(partial, off, 64);
    if ((t & 63) == 0) sh_red[t >> 6] = partial;
    __syncthreads();

    const float s = 1.0f / (512.0f * 511.0f);
    if (t == 0) {
        const float btot = sh_red[0] + sh_red[1] + sh_red[2] + sh_red[3];
        atomicAdd(out, btot * s);
    }

    if (i == 0) {
        // block 0 also folds in -(sum of logits) from A's partials
        __syncthreads();
        float sA = ws[PART_OFF + t] + ws[PART_OFF + t + 256];
        #pragma unroll
        for (int off = 32; off > 0; off >>= 1)
            sA += __shfl_xor(sA, off, 64);
        if ((t & 63) == 0) sh_red[t >> 6] = sA;
        __syncthreads();
        if (t == 0) {
            const float sumA = sh_red[0] + sh_red[1] + sh_red[2] + sh_red[3];
            atomicAdd(out, -sumA * s);
        }
    }
}

// ================= Fallback (round-1 fused kernel, needs no ws) =============
__global__ void init_out(float* out) { out[0] = 0.0f; }

__global__ __launch_bounds__(256) void rnc_row_kernel(
    const float* __restrict__ features, const float* __restrict__ labels,
    float* __restrict__ out)
{
    const int i = blockIdx.x;
    const int t = threadIdx.x;
    __shared__ float  sh_fi[D];
    __shared__ float2 sh_le[N];
    __shared__ float  sh_logit[N];
    __shared__ float  sh_red[4];

    const float* fi = frow(features, i);
    sh_fi[t] = fi[t];
    __syncthreads();
    const float lab_i = labels[i & 255];

    #pragma unroll
    for (int jj = 0; jj < 2; ++jj) {
        const int j = t + jj * 256;
        const float* fj = frow(features, j);
        float acc = 0.0f;
        #pragma unroll 4
        for (int d = 0; d < D; d += 4) {
            float4 v = *reinterpret_cast<const float4*>(fj + d);
            float d0 = sh_fi[d + 0] - v.x, d1 = sh_fi[d + 1] - v.y;
            float d2 = sh_fi[d + 2] - v.z, d3 = sh_fi[d + 3] - v.w;
            acc += d0 * d0 + d1 * d1 + d2 * d2 + d3 * d3;
        }
        float norm  = (acc > 0.0f) ? sqrtf(acc) : 0.0f;
        float logit = -norm * 0.5f;
        sh_logit[j] = logit;
        float e = (j == i) ? 0.0f : expf(logit);
        sh_le[j] = make_float2(fabsf(lab_i - labels[j & 255]), e);
    }
    __syncthreads();

    const int   k0 = t, k1 = t + 256;
    const float ldk0 = sh_le[k0].x, ldk1 = sh_le[k1].x;
    float neg0 = 0.0f, neg1 = 0.0f;
    #pragma unroll 8
    for (int j = 0; j < N; ++j) {
        float2 le = sh_le[j];
        neg0 += (le.x >= ldk0) ? le.y : 0.0f;
        neg1 += (le.x >= ldk1) ? le.y : 0.0f;
    }
    float partial = 0.0f;
    if (k0 != i) partial += sh_logit[k0] - logf(neg0);
    if (k1 != i) partial += sh_logit[k1] - logf(neg1);
    #pragma unroll
    for (int off = 32; off > 0; off >>= 1)
        partial += __shfl_down(partial, off, 64);
    if ((t & 63) == 0) sh_red[t >> 6] = partial;
    __syncthreads();
    if (t == 0)
        atomicAdd(out, (sh_red[0] + sh_red[1] + sh_red[2] + sh_red[3]) *
                       (-1.0f / ((float)N * (float)(N - 1))));
}

extern "C" void kernel_launch(void* const* d_in, const int* in_sizes, int n_in,
                              void* d_out, int out_size, void* d_ws, size_t ws_size,
                              hipStream_t stream) {
    const float* features = (const float*)d_in[0];  // (256, 2, 256) fp32
    const float* labels   = (const float*)d_in[1];  // (256, 1) fp32
    float* out = (float*)d_out;
    float* ws  = (float*)d_ws;

    if (ws_size >= WS_BYTES) {
        rnc_distA<<<512, 256, 0, stream>>>(features, ws, out);
        rnc_negB<<<512, 256, 0, stream>>>(labels, ws, out);
    } else {
        init_out<<<1, 1, 0, stream>>>(out);
        rnc_row_kernel<<<N, 256, 0, stream>>>(features, labels, out);
    }
}

// Round 8
// 73.413 us; speedup vs baseline: 1.1032x; 1.0857x over previous
//
#include <hip/hip_runtime.h>
#include <math.h>

#define N 512
#define D 256
// ws layout (round-3): E table 512x512 floats, then 1024 A-partials
#define E_OFF 0
#define PART_OFF (512 * 512)
#define WS_FLOATS (PART_OFF + 1024)
#define WS_BYTES (WS_FLOATS * sizeof(float))

__device__ __forceinline__ const float* frow(const float* F, int g) {
    // f[g][:] = features[(g%256), (g/256), :]
    return F + (size_t)(g & 255) * 512 + (size_t)(g >> 8) * 256;
}

// ================= Kernel A: verbatim round-3 dist kernel =================
// 1024 blocks = 64 i-groups x 16 j-slices; 256 thr = 32 j-cols x 8 d-slices.
// 4 blocks/CU, small register footprint (b[8] = 32 VGPR) — proven config.
// Block 0 thread 0 additionally zeroes out[0] (read only by next dispatch).
__global__ __launch_bounds__(256) void rnc_distA(
    const float* __restrict__ F, float* __restrict__ ws,
    float* __restrict__ out)
{
    const int i0 = (blockIdx.x >> 4) * 8;
    const int t  = threadIdx.x;
    const int ds = t & 7;
    const int gj = (blockIdx.x & 15) * 32 + (t >> 3);

    __shared__ float sh_fi[8 * 256];
    __shared__ float sh_red[4];

    if (blockIdx.x == 0 && t == 0) out[0] = 0.0f;

    #pragma unroll
    for (int r = 0; r < 8; ++r)
        sh_fi[r * 256 + (t ^ ((t >> 3) & 28))] = frow(F, i0 + r)[t];

    const float* fj = frow(F, gj);
    float4 b[8];
    #pragma unroll
    for (int q = 0; q < 8; ++q)
        b[q] = *reinterpret_cast<const float4*>(fj + ds * 32 + q * 4);

    __syncthreads();

    float acc[8] = {0, 0, 0, 0, 0, 0, 0, 0};
    #pragma unroll
    for (int q = 0; q < 8; ++q) {
        const int eb = ds * 32 + ((q * 4) ^ (ds << 2));   // swizzled read addr
        #pragma unroll
        for (int r = 0; r < 8; ++r) {
            const float4 a = *reinterpret_cast<const float4*>(&sh_fi[r * 256 + eb]);
            const float d0 = a.x - b[q].x, d1 = a.y - b[q].y;
            const float d2 = a.z - b[q].z, d3 = a.w - b[q].w;
            acc[r] += d0 * d0 + d1 * d1 + d2 * d2 + d3 * d3;
        }
    }
    #pragma unroll
    for (int r = 0; r < 8; ++r) {
        acc[r] += __shfl_xor(acc[r], 1, 64);
        acc[r] += __shfl_xor(acc[r], 2, 64);
        acc[r] += __shfl_xor(acc[r], 4, 64);
    }
    float v = acc[0];
    v = (ds == 1) ? acc[1] : v;  v = (ds == 2) ? acc[2] : v;
    v = (ds == 3) ? acc[3] : v;  v = (ds == 4) ? acc[4] : v;
    v = (ds == 5) ? acc[5] : v;  v = (ds == 6) ? acc[6] : v;
    v = (ds == 7) ? acc[7] : v;

    const int   gi    = i0 + ds;
    const float logit = -0.5f * sqrtf(v);      // TEMP=2; diag v is exactly 0
    ws[E_OFF + gi * 512 + gj] = (gj == gi) ? 0.0f : expf(logit);

    float slog = logit;                        // diag contributes -0.0
    #pragma unroll
    for (int off = 32; off > 0; off >>= 1)
        slog += __shfl_xor(slog, off, 64);
    if ((t & 63) == 0) sh_red[t >> 6] = slog;
    __syncthreads();
    if (t == 0)
        ws[PART_OFF + blockIdx.x] = sh_red[0] + sh_red[1] + sh_red[2] + sh_red[3];
}

// ================= Kernel B: round-3 neg kernel + merged finalize ============
// 512 blocks x 256 thr; block i handles row i (verbatim round-3 B body).
// Each block atomicAdds its scaled m*log(neg) sum; block 0 also reduces the
// 1024 A-partials (verbatim round-3 C arithmetic) and subtracts their sum.
__global__ __launch_bounds__(256) void rnc_negB(
    const float* __restrict__ labels, const float* __restrict__ ws,
    float* __restrict__ out)
{
    const int i = blockIdx.x;   // row 0..511
    const int t = threadIdx.x;  // k' = 0..255
    __shared__ float2 pr[256];
    __shared__ float  sh_red[4];

    const float lab_i = labels[i & 255];
    const float ldk   = fabsf(lab_i - labels[t]);
    // fold the two j-halves (exact single add, proven round 3)
    const float e2 = ws[E_OFF + i * 512 + t] + ws[E_OFF + i * 512 + t + 256];
    pr[t] = make_float2(ldk, e2);
    __syncthreads();

    float ng0 = 0, ng1 = 0, ng2 = 0, ng3 = 0;
    #pragma unroll 8
    for (int j = 0; j < 256; j += 4) {
        const float2 p0 = pr[j + 0], p1 = pr[j + 1];
        const float2 p2 = pr[j + 2], p3 = pr[j + 3];
        ng0 += (p0.x >= ldk) ? p0.y : 0.0f;
        ng1 += (p1.x >= ldk) ? p1.y : 0.0f;
        ng2 += (p2.x >= ldk) ? p2.y : 0.0f;
        ng3 += (p3.x >= ldk) ? p3.y : 0.0f;
    }
    const float neg = (ng0 + ng1) + (ng2 + ng3);
    const float m = (t == (i & 255)) ? 1.0f : 2.0f;  // class i&255 has 1 member
    float partial = m * logf(neg);

    #pragma unroll
    for (int off = 32; off > 0; off >>= 1)
        partial += __shfl_xor(partial, off, 64);
    if ((t & 63) == 0) sh_red[t >> 6] = partial;
    __syncthreads();

    const float s = 1.0f / (512.0f * 511.0f);
    if (t == 0) {
        const float btot = sh_red[0] + sh_red[1] + sh_red[2] + sh_red[3];
        atomicAdd(out, btot * s);
    }

    if (i == 0) {
        // block 0 folds in -(sum of logits): verbatim round-3 C reduction
        __syncthreads();   // block-uniform branch: legal
        float sA = ws[PART_OFF + t] + ws[PART_OFF + t + 256] +
                   ws[PART_OFF + t + 512] + ws[PART_OFF + t + 768];
        #pragma unroll
        for (int off = 32; off > 0; off >>= 1)
            sA += __shfl_xor(sA, off, 64);
        if ((t & 63) == 0) sh_red[t >> 6] = sA;
        __syncthreads();
        if (t == 0) {
            const float sumA = sh_red[0] + sh_red[1] + sh_red[2] + sh_red[3];
            atomicAdd(out, -sumA * s);
        }
    }
}

// ================= Fallback (round-1 fused kernel, needs no ws) =============
__global__ void init_out(float* out) { out[0] = 0.0f; }

__global__ __launch_bounds__(256) void rnc_row_kernel(
    const float* __restrict__ features, const float* __restrict__ labels,
    float* __restrict__ out)
{
    const int i = blockIdx.x;
    const int t = threadIdx.x;
    __shared__ float  sh_fi[D];
    __shared__ float2 sh_le[N];
    __shared__ float  sh_logit[N];
    __shared__ float  sh_red[4];

    const float* fi = frow(features, i);
    sh_fi[t] = fi[t];
    __syncthreads();
    const float lab_i = labels[i & 255];

    #pragma unroll
    for (int jj = 0; jj < 2; ++jj) {
        const int j = t + jj * 256;
        const float* fj = frow(features, j);
        float acc = 0.0f;
        #pragma unroll 4
        for (int d = 0; d < D; d += 4) {
            float4 v = *reinterpret_cast<const float4*>(fj + d);
            float d0 = sh_fi[d + 0] - v.x, d1 = sh_fi[d + 1] - v.y;
            float d2 = sh_fi[d + 2] - v.z, d3 = sh_fi[d + 3] - v.w;
            acc += d0 * d0 + d1 * d1 + d2 * d2 + d3 * d3;
        }
        float norm  = (acc > 0.0f) ? sqrtf(acc) : 0.0f;
        float logit = -norm * 0.5f;
        sh_logit[j] = logit;
        float e = (j == i) ? 0.0f : expf(logit);
        sh_le[j] = make_float2(fabsf(lab_i - labels[j & 255]), e);
    }
    __syncthreads();

    const int   k0 = t, k1 = t + 256;
    const float ldk0 = sh_le[k0].x, ldk1 = sh_le[k1].x;
    float neg0 = 0.0f, neg1 = 0.0f;
    #pragma unroll 8
    for (int j = 0; j < N; ++j) {
        float2 le = sh_le[j];
        neg0 += (le.x >= ldk0) ? le.y : 0.0f;
        neg1 += (le.x >= ldk1) ? le.y : 0.0f;
    }
    float partial = 0.0f;
    if (k0 != i) partial += sh_logit[k0] - logf(neg0);
    if (k1 != i) partial += sh_logit[k1] - logf(neg1);
    #pragma unroll
    for (int off = 32; off > 0; off >>= 1)
        partial += __shfl_down(partial, off, 64);
    if ((t & 63) == 0) sh_red[t >> 6] = partial;
    __syncthreads();
    if (t == 0)
        atomicAdd(out, (sh_red[0] + sh_red[1] + sh_red[2] + sh_red[3]) *
                       (-1.0f / ((float)N * (float)(N - 1))));
}

extern "C" void kernel_launch(void* const* d_in, const int* in_sizes, int n_in,
                              void* d_out, int out_size, void* d_ws, size_t ws_size,
                              hipStream_t stream) {
    const float* features = (const float*)d_in[0];  // (256, 2, 256) fp32
    const float* labels   = (const float*)d_in[1];  // (256, 1) fp32
    float* out = (float*)d_out;
    float* ws  = (float*)d_ws;

    if (ws_size >= WS_BYTES) {
        rnc_distA<<<1024, 256, 0, stream>>>(features, ws, out);
        rnc_negB<<<512, 256, 0, stream>>>(labels, ws, out);
    } else {
        init_out<<<1, 1, 0, stream>>>(out);
        rnc_row_kernel<<<N, 256, 0, stream>>>(features, labels, out);
    }
}

// Round 9
// 72.174 us; speedup vs baseline: 1.1221x; 1.0172x over previous
//
#include <hip/hip_runtime.h>
#include <math.h>

#define N 512
#define D 256
// ws layout (round-3): E table 512x512 floats, 1024 A-partials, 512 B-partials
#define E_OFF 0
#define PART_OFF (512 * 512)
#define WS_FLOATS (PART_OFF + 1024 + 512)
#define WS_BYTES (WS_FLOATS * sizeof(float))

__device__ __forceinline__ const float* frow(const float* F, int g) {
    // f[g][:] = features[(g%256), (g/256), :]
    return F + (size_t)(g & 255) * 512 + (size_t)(g >> 8) * 256;
}

// ================= Kernel A: dist, 2 cols/thread =================
// 1024 blocks = 128 i-groups (4 rows) x 8 j-slices (64 cols); 256 thr =
// 32 col-pairs x 8 d-slices. Each fi ds_read_b128 feeds BOTH columns ->
// LDS wave-instructions halved vs round 3 at identical occupancy (4/CU).
// After the 8-lane xor-reduce, lane ds owns (row = ds&3, col = j0 + (ds>>2)).
__global__ __launch_bounds__(256, 4) void rnc_distA(
    const float* __restrict__ F, float* __restrict__ ws)
{
    const int blk = blockIdx.x;        // 0..1023
    const int t   = threadIdx.x;       // 0..255
    const int ds  = t & 7;             // 0..7 : d-slice (32 floats)
    const int cg  = t >> 3;            // 0..31 : column pair
    const int i0  = (blk >> 3) * 4;    // 4-row i-group
    const int j0  = (blk & 7) * 64 + cg * 2;   // even col; j1 = j0+1

    __shared__ float sh_fi[4 * 256];
    __shared__ float sh_red[4];

    // stage 4 fi rows, XOR-swizzled (same pattern as round 3, verified)
    #pragma unroll
    for (int r = 0; r < 4; ++r)
        sh_fi[r * 256 + (t ^ ((t >> 3) & 28))] = frow(F, i0 + r)[t];

    // preload both fj column slices (128B contiguous per lane each)
    const float* fj0 = frow(F, j0);
    const float* fj1 = frow(F, j0 + 1);
    float4 b0[8], b1[8];
    #pragma unroll
    for (int q = 0; q < 8; ++q) {
        b0[q] = *reinterpret_cast<const float4*>(fj0 + ds * 32 + q * 4);
        b1[q] = *reinterpret_cast<const float4*>(fj1 + ds * 32 + q * 4);
    }

    __syncthreads();

    float acc0[4] = {0, 0, 0, 0};
    float acc1[4] = {0, 0, 0, 0};
    #pragma unroll
    for (int q = 0; q < 8; ++q) {
        const int eb = ds * 32 + ((q * 4) ^ (ds << 2));   // swizzled read addr
        #pragma unroll
        for (int r = 0; r < 4; ++r) {
            const float4 a = *reinterpret_cast<const float4*>(&sh_fi[r * 256 + eb]);
            const float e00 = a.x - b0[q].x, e01 = a.y - b0[q].y;
            const float e02 = a.z - b0[q].z, e03 = a.w - b0[q].w;
            acc0[r] += e00 * e00 + e01 * e01 + e02 * e02 + e03 * e03;
            const float e10 = a.x - b1[q].x, e11 = a.y - b1[q].y;
            const float e12 = a.z - b1[q].z, e13 = a.w - b1[q].w;
            acc1[r] += e10 * e10 + e11 * e11 + e12 * e12 + e13 * e13;
        }
    }

    // reduce partial dots across the 8 d-slice lanes (same op order as r3)
    #pragma unroll
    for (int r = 0; r < 4; ++r) {
        acc0[r] += __shfl_xor(acc0[r], 1, 64);
        acc0[r] += __shfl_xor(acc0[r], 2, 64);
        acc0[r] += __shfl_xor(acc0[r], 4, 64);
        acc1[r] += __shfl_xor(acc1[r], 1, 64);
        acc1[r] += __shfl_xor(acc1[r], 2, 64);
        acc1[r] += __shfl_xor(acc1[r], 4, 64);
    }

    // lane ds -> (row = ds&3, col-half = ds>>2); static select chains
    const int rsel = ds & 3;
    float v0 = acc0[0];
    v0 = (rsel == 1) ? acc0[1] : v0;
    v0 = (rsel == 2) ? acc0[2] : v0;
    v0 = (rsel == 3) ? acc0[3] : v0;
    float v1 = acc1[0];
    v1 = (rsel == 1) ? acc1[1] : v1;
    v1 = (rsel == 2) ? acc1[2] : v1;
    v1 = (rsel == 3) ? acc1[3] : v1;
    const float v  = (ds >> 2) ? v1 : v0;
    const int   gi = i0 + rsel;
    const int   gj = j0 + (ds >> 2);

    const float logit = -0.5f * sqrtf(v);      // TEMP=2; diag v is exactly 0
    ws[E_OFF + gi * 512 + gj] = (gj == gi) ? 0.0f : expf(logit);

    // per-block logit sum (diag contributes -0.0)
    float slog = logit;
    #pragma unroll
    for (int off = 32; off > 0; off >>= 1)
        slog += __shfl_xor(slog, off, 64);
    if ((t & 63) == 0) sh_red[t >> 6] = slog;
    __syncthreads();
    if (t == 0)
        ws[PART_OFF + blk] = sh_red[0] + sh_red[1] + sh_red[2] + sh_red[3];
}

// ================= Kernel B: neg + log (b128-friendly LDS) =================
__global__ __launch_bounds__(256) void rnc_negB(
    const float* __restrict__ labels, float* __restrict__ ws)
{
    const int i = blockIdx.x;   // row 0..511
    const int t = threadIdx.x;  // k' = 0..255
    __shared__ __align__(16) float sh_ld[256];
    __shared__ __align__(16) float sh_e2[256];
    __shared__ float sh_red[4];

    const float lab_i = labels[i & 255];
    const float ldk   = fabsf(lab_i - labels[t]);
    // fold the two j-halves (exact single add, proven round 3)
    sh_ld[t] = ldk;
    sh_e2[t] = ws[E_OFF + i * 512 + t] + ws[E_OFF + i * 512 + t + 256];
    __syncthreads();

    float ng0 = 0, ng1 = 0, ng2 = 0, ng3 = 0;
    #pragma unroll 8
    for (int j = 0; j < 256; j += 4) {
        const float4 ldv = *reinterpret_cast<const float4*>(&sh_ld[j]);
        const float4 ev  = *reinterpret_cast<const float4*>(&sh_e2[j]);
        ng0 += (ldv.x >= ldk) ? ev.x : 0.0f;
        ng1 += (ldv.y >= ldk) ? ev.y : 0.0f;
        ng2 += (ldv.z >= ldk) ? ev.z : 0.0f;
        ng3 += (ldv.w >= ldk) ? ev.w : 0.0f;
    }
    const float neg = (ng0 + ng1) + (ng2 + ng3);
    const float m = (t == (i & 255)) ? 1.0f : 2.0f;  // class i&255 has 1 member
    float partial = m * logf(neg);

    #pragma unroll
    for (int off = 32; off > 0; off >>= 1)
        partial += __shfl_xor(partial, off, 64);
    if ((t & 63) == 0) sh_red[t >> 6] = partial;
    __syncthreads();
    if (t == 0)
        ws[PART_OFF + 1024 + i] = sh_red[0] + sh_red[1] + sh_red[2] + sh_red[3];
}

// ================= Kernel C: final reduction (verbatim round 3) =============
__global__ __launch_bounds__(256) void rnc_final_kernel(
    const float* __restrict__ ws, float* __restrict__ out)
{
    const int t = threadIdx.x;
    __shared__ float sa[4], sb[4];
    float sA = ws[PART_OFF + t] + ws[PART_OFF + t + 256] +
               ws[PART_OFF + t + 512] + ws[PART_OFF + t + 768];
    float sB = ws[PART_OFF + 1024 + t] + ws[PART_OFF + 1024 + t + 256];
    #pragma unroll
    for (int off = 32; off > 0; off >>= 1) {
        sA += __shfl_xor(sA, off, 64);
        sB += __shfl_xor(sB, off, 64);
    }
    if ((t & 63) == 0) { sa[t >> 6] = sA; sb[t >> 6] = sB; }
    __syncthreads();
    if (t == 0)
        out[0] = ((sb[0] + sb[1] + sb[2] + sb[3]) -
                  (sa[0] + sa[1] + sa[2] + sa[3])) * (1.0f / (512.0f * 511.0f));
}

// ================= Fallback (round-1 fused kernel, needs no ws) =============
__global__ void init_out(float* out) { out[0] = 0.0f; }

__global__ __launch_bounds__(256) void rnc_row_kernel(
    const float* __restrict__ features, const float* __restrict__ labels,
    float* __restrict__ out)
{
    const int i = blockIdx.x;
    const int t = threadIdx.x;
    __shared__ float  sh_fi[D];
    __shared__ float2 sh_le[N];
    __shared__ float  sh_logit[N];
    __shared__ float  sh_red[4];

    const float* fi = frow(features, i);
    sh_fi[t] = fi[t];
    __syncthreads();
    const float lab_i = labels[i & 255];

    #pragma unroll
    for (int jj = 0; jj < 2; ++jj) {
        const int j = t + jj * 256;
        const float* fj = frow(features, j);
        float acc = 0.0f;
        #pragma unroll 4
        for (int d = 0; d < D; d += 4) {
            float4 v = *reinterpret_cast<const float4*>(fj + d);
            float d0 = sh_fi[d + 0] - v.x, d1 = sh_fi[d + 1] - v.y;
            float d2 = sh_fi[d + 2] - v.z, d3 = sh_fi[d + 3] - v.w;
            acc += d0 * d0 + d1 * d1 + d2 * d2 + d3 * d3;
        }
        float norm  = (acc > 0.0f) ? sqrtf(acc) : 0.0f;
        float logit = -norm * 0.5f;
        sh_logit[j] = logit;
        float e = (j == i) ? 0.0f : expf(logit);
        sh_le[j] = make_float2(fabsf(lab_i - labels[j & 255]), e);
    }
    __syncthreads();

    const int   k0 = t, k1 = t + 256;
    const float ldk0 = sh_le[k0].x, ldk1 = sh_le[k1].x;
    float neg0 = 0.0f, neg1 = 0.0f;
    #pragma unroll 8
    for (int j = 0; j < N; ++j) {
        float2 le = sh_le[j];
        neg0 += (le.x >= ldk0) ? le.y : 0.0f;
        neg1 += (le.x >= ldk1) ? le.y : 0.0f;
    }
    float partial = 0.0f;
    if (k0 != i) partial += sh_logit[k0] - logf(neg0);
    if (k1 != i) partial += sh_logit[k1] - logf(neg1);
    #pragma unroll
    for (int off = 32; off > 0; off >>= 1)
        partial += __shfl_down(partial, off, 64);
    if ((t & 63) == 0) sh_red[t >> 6] = partial;
    __syncthreads();
    if (t == 0)
        atomicAdd(out, (sh_red[0] + sh_red[1] + sh_red[2] + sh_red[3]) *
                       (-1.0f / ((float)N * (float)(N - 1))));
}

extern "C" void kernel_launch(void* const* d_in, const int* in_sizes, int n_in,
                              void* d_out, int out_size, void* d_ws, size_t ws_size,
                              hipStream_t stream) {
    const float* features = (const float*)d_in[0];  // (256, 2, 256) fp32
    const float* labels   = (const float*)d_in[1];  // (256, 1) fp32
    float* out = (float*)d_out;
    float* ws  = (float*)d_ws;

    if (ws_size >= WS_BYTES) {
        rnc_distA<<<1024, 256, 0, stream>>>(features, ws);
        rnc_negB<<<512, 256, 0, stream>>>(labels, ws);
        rnc_final_kernel<<<1, 256, 0, stream>>>(ws, out);
    } else {
        init_out<<<1, 1, 0, stream>>>(out);
        rnc_row_kernel<<<N, 256, 0, stream>>>(features, labels, out);
    }
}

// Round 10
// 69.111 us; speedup vs baseline: 1.1719x; 1.0443x over previous
//
#include <hip/hip_runtime.h>
#include <math.h>

#define N 512
#define D 256
#define E_OFF 0                      // E table: 512*512 floats (e values, diag = 0)
#define PART_OFF (512 * 512)         // partials: 1024 (A: logit sums) + 512 (B: log terms)
#define WS_FLOATS (PART_OFF + 1024 + 512)
#define WS_BYTES (WS_FLOATS * sizeof(float))

__device__ __forceinline__ const float* frow(const float* F, int g) {
    // f[g][:] = features[(g%256), (g/256), :]
    return F + (size_t)(g & 255) * 512 + (size_t)(g >> 8) * 256;
}

// ---------------- Kernel A: pairwise dist -> E table + per-block logit sums ----
// 1024 blocks = 64 i-groups x 16 j-slices; 256 thr = 32 j-cols x 8 d-slices.
// After the 8-lane dot-product reduce, lane ds takes row r = ds, so all 64
// lanes of a wave do sqrt/exp/store (8 rows x 8 cols). No atomics.
// [Measured best: rounds 3/9 A/B'd all variants — 2-col/thread, 4-row groups,
//  merged dispatches all regress. Do not restructure without new counters.]
__global__ __launch_bounds__(256) void rnc_dist_kernel(
    const float* __restrict__ F, float* __restrict__ ws)
{
    const int i0 = (blockIdx.x >> 4) * 8;
    const int t  = threadIdx.x;
    const int jl = t >> 3;     // 0..31 : j within block
    const int ds = t & 7;      // 0..7  : d-slice
    const int gj = (blockIdx.x & 15) * 32 + jl;

    __shared__ float sh_fi[8 * 256];
    __shared__ float sh_red[4];

    // stage 8 fi rows, XOR-swizzled (verified conflict-free)
    #pragma unroll
    for (int r = 0; r < 8; ++r)
        sh_fi[r * 256 + (t ^ ((t >> 3) & 28))] = frow(F, i0 + r)[t];

    // preload this thread's fj slice (32 floats)
    const float* fj = frow(F, gj);
    float4 b[8];
    #pragma unroll
    for (int q = 0; q < 8; ++q)
        b[q] = *reinterpret_cast<const float4*>(fj + ds * 32 + q * 4);

    __syncthreads();

    float acc[8] = {0, 0, 0, 0, 0, 0, 0, 0};
    #pragma unroll
    for (int q = 0; q < 8; ++q) {
        const int eb = ds * 32 + ((q * 4) ^ (ds << 2));   // swizzled read addr
        #pragma unroll
        for (int r = 0; r < 8; ++r) {
            const float4 a = *reinterpret_cast<const float4*>(&sh_fi[r * 256 + eb]);
            const float d0 = a.x - b[q].x, d1 = a.y - b[q].y;
            const float d2 = a.z - b[q].z, d3 = a.w - b[q].w;
            acc[r] += d0 * d0 + d1 * d1 + d2 * d2 + d3 * d3;
        }
    }

    // reduce each row's partial dot across the 8-lane group
    #pragma unroll
    for (int r = 0; r < 8; ++r) {
        acc[r] += __shfl_xor(acc[r], 1, 64);
        acc[r] += __shfl_xor(acc[r], 2, 64);
        acc[r] += __shfl_xor(acc[r], 4, 64);
    }

    // lane ds owns row r = ds (static select chain -> cndmask, no scratch)
    float v = acc[0];
    v = (ds == 1) ? acc[1] : v;
    v = (ds == 2) ? acc[2] : v;
    v = (ds == 3) ? acc[3] : v;
    v = (ds == 4) ? acc[4] : v;
    v = (ds == 5) ? acc[5] : v;
    v = (ds == 6) ? acc[6] : v;
    v = (ds == 7) ? acc[7] : v;

    const int   gi    = i0 + ds;
    const float logit = -0.5f * sqrtf(v);            // TEMP=2; v_ii is exactly 0
    ws[E_OFF + gi * 512 + gj] = (gj == gi) ? 0.0f : expf(logit);

    // sum of logits over this block's 8x32 tile (diag contributes -0.0)
    float slog = logit;
    #pragma unroll
    for (int off = 32; off > 0; off >>= 1)
        slog += __shfl_xor(slog, off, 64);
    if ((t & 63) == 0) sh_red[t >> 6] = slog;
    __syncthreads();
    if (t == 0)
        ws[PART_OFF + blockIdx.x] = sh_red[0] + sh_red[1] + sh_red[2] + sh_red[3];
}

// ---------------- Kernel B: neg + log, folded to 256 columns ----------------
__global__ __launch_bounds__(256) void rnc_neg_kernel(
    const float* __restrict__ labels, float* __restrict__ ws)
{
    const int i = blockIdx.x;   // row 0..511
    const int t = threadIdx.x;  // k' = 0..255
    __shared__ float2 pr[256];  // {ld_j', E2[i][j']}
    __shared__ float  sh_red[4];

    const float lab_i = labels[i & 255];
    const float ldk   = fabsf(lab_i - labels[t]);
    // fold the two j-halves (exact: single 2-addend add, order-invariant)
    const float e2 = ws[E_OFF + i * 512 + t] + ws[E_OFF + i * 512 + t + 256];
    pr[t] = make_float2(ldk, e2);
    __syncthreads();

    float ng0 = 0, ng1 = 0, ng2 = 0, ng3 = 0;
    #pragma unroll 8
    for (int j = 0; j < 256; j += 4) {
        const float2 p0 = pr[j + 0], p1 = pr[j + 1];
        const float2 p2 = pr[j + 2], p3 = pr[j + 3];
        ng0 += (p0.x >= ldk) ? p0.y : 0.0f;
        ng1 += (p1.x >= ldk) ? p1.y : 0.0f;
        ng2 += (p2.x >= ldk) ? p2.y : 0.0f;
        ng3 += (p3.x >= ldk) ? p3.y : 0.0f;
    }
    const float neg = (ng0 + ng1) + (ng2 + ng3);
    // class k' = i&255 has 1 member among k != i, all other classes 2
    const float m = (t == (i & 255)) ? 1.0f : 2.0f;
    float partial = m * logf(neg);

    #pragma unroll
    for (int off = 32; off > 0; off >>= 1)
        partial += __shfl_xor(partial, off, 64);
    if ((t & 63) == 0) sh_red[t >> 6] = partial;
    __syncthreads();
    if (t == 0)
        ws[PART_OFF + 1024 + i] = sh_red[0] + sh_red[1] + sh_red[2] + sh_red[3];
}

// ---------------- Kernel C: final reduction ----------------
__global__ __launch_bounds__(256) void rnc_final_kernel(
    const float* __restrict__ ws, float* __restrict__ out)
{
    const int t = threadIdx.x;
    __shared__ float sa[4], sb[4];

    float sA = ws[PART_OFF + t] + ws[PART_OFF + t + 256] +
               ws[PART_OFF + t + 512] + ws[PART_OFF + t + 768];
    float sB = ws[PART_OFF + 1024 + t] + ws[PART_OFF + 1024 + t + 256];

    #pragma unroll
    for (int off = 32; off > 0; off >>= 1) {
        sA += __shfl_xor(sA, off, 64);
        sB += __shfl_xor(sB, off, 64);
    }
    if ((t & 63) == 0) { sa[t >> 6] = sA; sb[t >> 6] = sB; }
    __syncthreads();
    if (t == 0) {
        const float sumA = sa[0] + sa[1] + sa[2] + sa[3];  // sum of logits
        const float sumB = sb[0] + sb[1] + sb[2] + sb[3];  // sum of m*log(neg)
        out[0] = (sumB - sumA) * (1.0f / (512.0f * 511.0f));
    }
}

// ---------------- Fallback (round-1 fused kernel, needs no ws) ----------------
__global__ void init_out(float* out) { out[0] = 0.0f; }

__global__ __launch_bounds__(256) void rnc_row_kernel(
    const float* __restrict__ features, const float* __restrict__ labels,
    float* __restrict__ out)
{
    const int i = blockIdx.x;
    const int t = threadIdx.x;
    __shared__ float  sh_fi[D];
    __shared__ float2 sh_le[N];
    __shared__ float  sh_logit[N];
    __shared__ float  sh_red[4];

    const float* fi = frow(features, i);
    sh_fi[t] = fi[t];
    __syncthreads();
    const float lab_i = labels[i & 255];

    #pragma unroll
    for (int jj = 0; jj < 2; ++jj) {
        const int j = t + jj * 256;
        const float* fj = frow(features, j);
        float acc = 0.0f;
        #pragma unroll 4
        for (int d = 0; d < D; d += 4) {
            float4 v = *reinterpret_cast<const float4*>(fj + d);
            float d0 = sh_fi[d + 0] - v.x, d1 = sh_fi[d + 1] - v.y;
            float d2 = sh_fi[d + 2] - v.z, d3 = sh_fi[d + 3] - v.w;
            acc += d0 * d0 + d1 * d1 + d2 * d2 + d3 * d3;
        }
        float norm  = (acc > 0.0f) ? sqrtf(acc) : 0.0f;
        float logit = -norm * 0.5f;
        sh_logit[j] = logit;
        float e = (j == i) ? 0.0f : expf(logit);
        sh_le[j] = make_float2(fabsf(lab_i - labels[j & 255]), e);
    }
    __syncthreads();

    const int   k0 = t, k1 = t + 256;
    const float ldk0 = sh_le[k0].x, ldk1 = sh_le[k1].x;
    float neg0 = 0.0f, neg1 = 0.0f;
    #pragma unroll 8
    for (int j = 0; j < N; ++j) {
        float2 le = sh_le[j];
        neg0 += (le.x >= ldk0) ? le.y : 0.0f;
        neg1 += (le.x >= ldk1) ? le.y : 0.0f;
    }
    float partial = 0.0f;
    if (k0 != i) partial += sh_logit[k0] - logf(neg0);
    if (k1 != i) partial += sh_logit[k1] - logf(neg1);
    #pragma unroll
    for (int off = 32; off > 0; off >>= 1)
        partial += __shfl_down(partial, off, 64);
    if ((t & 63) == 0) sh_red[t >> 6] = partial;
    __syncthreads();
    if (t == 0)
        atomicAdd(out, (sh_red[0] + sh_red[1] + sh_red[2] + sh_red[3]) *
                       (-1.0f / ((float)N * (float)(N - 1))));
}

extern "C" void kernel_launch(void* const* d_in, const int* in_sizes, int n_in,
                              void* d_out, int out_size, void* d_ws, size_t ws_size,
                              hipStream_t stream) {
    const float* features = (const float*)d_in[0];  // (256, 2, 256) fp32
    const float* labels   = (const float*)d_in[1];  // (256, 1) fp32
    float* out = (float*)d_out;

    if (ws_size >= WS_BYTES) {
        float* ws = (float*)d_ws;
        rnc_dist_kernel<<<1024, 256, 0, stream>>>(features, ws);
        rnc_neg_kernel<<<512, 256, 0, stream>>>(labels, ws);
        rnc_final_kernel<<<1, 256, 0, stream>>>(ws, out);
    } else {
        init_out<<<1, 1, 0, stream>>>(out);
        rnc_row_kernel<<<N, 256, 0, stream>>>(features, labels, out);
    }
}